// Round 1
// baseline (1633.289 us; speedup 1.0000x reference)
//
#include <hip/hip_runtime.h>
#include <math.h>

#define S_LEN 512
#define D_DIM 256

// ---------------------------------------------------------------------------
// K1/K4: y = x + x@W + b   for [512,256]@[256,256]. 8 rows per block.
// ---------------------------------------------------------------------------
__global__ __launch_bounds__(256) void linres_kernel(
    const float* __restrict__ x, const float* __restrict__ W,
    const float* __restrict__ b, float* __restrict__ y)
{
    __shared__ float xs[8][D_DIM];
    const int tid = threadIdx.x;
    const int r0 = blockIdx.x * 8;

    #pragma unroll
    for (int t = 0; t < 8; ++t)
        xs[t][tid] = x[(r0 + t) * D_DIM + tid];
    __syncthreads();

    float acc[8];
    const float bv = b[tid];
    #pragma unroll
    for (int i = 0; i < 8; ++i)
        acc[i] = xs[i][tid] + bv;          // residual + bias

    #pragma unroll 4
    for (int e = 0; e < D_DIM; ++e) {
        const float w = W[e * D_DIM + tid];
        #pragma unroll
        for (int i = 0; i < 8; ++i)
            acc[i] += xs[i][e] * w;
    }
    #pragma unroll
    for (int i = 0; i < 8; ++i)
        y[(r0 + i) * D_DIM + tid] = acc[i];
}

// ---------------------------------------------------------------------------
// K2: per-sk swishmax stats. One block per sk (512 blocks, 256 threads).
// Computes m[sk,d] = max_sq L, S[sk,d] = sum_sq |L| exp(L-m).
// L[sq,d] = sum_e (q[sq,e]*k[e]) * Wl[e,d] + q[sq,d]*k[d] + bl[d]
// Thread owns cols d = dg + 32*j (j=0..7), rows sg*8+i within each 64-sq tile.
// ---------------------------------------------------------------------------
__global__ __launch_bounds__(256) void stats_kernel(
    const float* __restrict__ qbuf, const float* __restrict__ kbuf,
    const float* __restrict__ Wl, const float* __restrict__ bl,
    float* __restrict__ mbuf, float* __restrict__ sbuf)
{
    __shared__ float k_sh[D_DIM];
    __shared__ float qs[64][33];       // (q*k)-scaled tile, transposed-free pitch 33
    __shared__ float wl[32][D_DIM];    // Wl e-chunk
    __shared__ float red_m[8][D_DIM];
    __shared__ float red_s[8][D_DIM];

    const int tid = threadIdx.x;
    const int dg = tid & 31, sg = tid >> 5;
    const int sk = blockIdx.x;

    k_sh[tid] = kbuf[sk * D_DIM + tid];

    float m_loc[8], s_loc[8];
    #pragma unroll
    for (int j = 0; j < 8; ++j) { m_loc[j] = -INFINITY; s_loc[j] = 0.f; }

    for (int t8 = 0; t8 < 8; ++t8) {
        const int sq0 = t8 * 64;
        float acc[8][8];
        #pragma unroll
        for (int i = 0; i < 8; ++i)
            #pragma unroll
            for (int j = 0; j < 8; ++j) acc[i][j] = 0.f;

        for (int eb = 0; eb < 8; ++eb) {
            const int e0 = eb * 32;
            __syncthreads();
            {   // stage scaled q chunk: qs[i][e] = q[sq0+i][e0+e] * k[e0+e]
                const int e = tid & 31, ib = tid >> 5;
                const float kv = k_sh[e0 + e];
                #pragma unroll
                for (int r = 0; r < 8; ++r) {
                    const int i = ib + 8 * r;
                    qs[i][e] = qbuf[(sq0 + i) * D_DIM + e0 + e] * kv;
                }
            }
            {   // stage Wl chunk: wl[r][d]
                #pragma unroll
                for (int r = 0; r < 32; ++r)
                    wl[r][tid] = Wl[(e0 + r) * D_DIM + tid];
            }
            __syncthreads();

            #pragma unroll 8
            for (int e = 0; e < 32; ++e) {
                float a[8], w[8];
                #pragma unroll
                for (int i = 0; i < 8; ++i) a[i] = qs[sg * 8 + i][e];
                #pragma unroll
                for (int j = 0; j < 8; ++j) w[j] = wl[e][dg + 32 * j];
                #pragma unroll
                for (int i = 0; i < 8; ++i)
                    #pragma unroll
                    for (int j = 0; j < 8; ++j)
                        acc[i][j] += a[i] * w[j];
            }
        }

        // finalize tile: diag + bias, online max/abs-exp-sum over this tile's rows
        #pragma unroll
        for (int j = 0; j < 8; ++j) {
            const int d = dg + 32 * j;
            const float kd = k_sh[d];
            const float blv = bl[d];
            float Lv[8];
            float cmax = -INFINITY;
            #pragma unroll
            for (int i = 0; i < 8; ++i) {
                const int row = sq0 + sg * 8 + i;
                const float L = acc[i][j] + qbuf[row * D_DIM + d] * kd + blv;
                Lv[i] = L;
                cmax = fmaxf(cmax, L);
            }
            const float nm = fmaxf(m_loc[j], cmax);
            s_loc[j] *= __expf(m_loc[j] - nm);
            #pragma unroll
            for (int i = 0; i < 8; ++i)
                s_loc[j] += fabsf(Lv[i]) * __expf(Lv[i] - nm);
            m_loc[j] = nm;
        }
    }

    // reduce the 8 sg-groups per column
    __syncthreads();
    #pragma unroll
    for (int j = 0; j < 8; ++j) {
        red_m[sg][dg + 32 * j] = m_loc[j];
        red_s[sg][dg + 32 * j] = s_loc[j];
    }
    __syncthreads();
    if (sg == 0) {
        #pragma unroll
        for (int j = 0; j < 8; ++j) {
            const int d = dg + 32 * j;
            float M = red_m[0][d];
            #pragma unroll
            for (int g = 1; g < 8; ++g) M = fmaxf(M, red_m[g][d]);
            float Ssum = 0.f;
            #pragma unroll
            for (int g = 0; g < 8; ++g)
                Ssum += red_s[g][d] * __expf(red_m[g][d] - M);
            mbuf[sk * D_DIM + d] = M;
            sbuf[sk * D_DIM + d] = Ssum;
        }
    }
}

// ---------------------------------------------------------------------------
// K3: recompute L, apply swishmax scale, accumulate value_sum over sk.
// Grid: (8 sq-tiles, 64 sk-chunks of 8). One atomicAdd per elem per block.
// ---------------------------------------------------------------------------
__global__ __launch_bounds__(256) void accum_kernel(
    const float* __restrict__ qbuf, const float* __restrict__ kbuf,
    const float* __restrict__ vbuf, const float* __restrict__ Wl,
    const float* __restrict__ bl, const float* __restrict__ mbuf,
    const float* __restrict__ sbuf, float* __restrict__ vs)
{
    __shared__ float k_sh[D_DIM];
    __shared__ float qs[64][33];
    __shared__ float wl[32][D_DIM];

    const int tid = threadIdx.x;
    const int dg = tid & 31, sg = tid >> 5;
    const int sq0 = blockIdx.x * 64;
    const int sk0 = blockIdx.y * 8;

    float oacc[8][8];
    #pragma unroll
    for (int i = 0; i < 8; ++i)
        #pragma unroll
        for (int j = 0; j < 8; ++j) oacc[i][j] = 0.f;

    for (int sk = sk0; sk < sk0 + 8; ++sk) {
        __syncthreads();                 // previous epilogue done before k_sh rewrite
        k_sh[tid] = kbuf[sk * D_DIM + tid];

        float acc[8][8];
        #pragma unroll
        for (int i = 0; i < 8; ++i)
            #pragma unroll
            for (int j = 0; j < 8; ++j) acc[i][j] = 0.f;

        for (int eb = 0; eb < 8; ++eb) {
            const int e0 = eb * 32;
            __syncthreads();
            {
                const int e = tid & 31, ib = tid >> 5;
                const float kv = k_sh[e0 + e];
                #pragma unroll
                for (int r = 0; r < 8; ++r) {
                    const int i = ib + 8 * r;
                    qs[i][e] = qbuf[(sq0 + i) * D_DIM + e0 + e] * kv;
                }
            }
            {
                #pragma unroll
                for (int r = 0; r < 32; ++r)
                    wl[r][tid] = Wl[(e0 + r) * D_DIM + tid];
            }
            __syncthreads();

            #pragma unroll 8
            for (int e = 0; e < 32; ++e) {
                float a[8], w[8];
                #pragma unroll
                for (int i = 0; i < 8; ++i) a[i] = qs[sg * 8 + i][e];
                #pragma unroll
                for (int j = 0; j < 8; ++j) w[j] = wl[e][dg + 32 * j];
                #pragma unroll
                for (int i = 0; i < 8; ++i)
                    #pragma unroll
                    for (int j = 0; j < 8; ++j)
                        acc[i][j] += a[i] * w[j];
            }
        }

        // epilogue for this sk: scale by swishmax, weight by v, accumulate
        #pragma unroll
        for (int j = 0; j < 8; ++j) {
            const int d = dg + 32 * j;
            const float kd = k_sh[d];
            const float blv = bl[d];
            const float mv = mbuf[sk * D_DIM + d];
            const float inv = 1.0f / (sbuf[sk * D_DIM + d] + 1.0f);
            const float vv = vbuf[sk * D_DIM + d];
            #pragma unroll
            for (int i = 0; i < 8; ++i) {
                const int row = sq0 + sg * 8 + i;
                const float L = acc[i][j] + qbuf[row * D_DIM + d] * kd + blv;
                const float p = L * __expf(L - mv) * inv;
                oacc[i][j] += vv * p;
            }
        }
    }

    #pragma unroll
    for (int i = 0; i < 8; ++i) {
        const int row = sq0 + sg * 8 + i;
        #pragma unroll
        for (int j = 0; j < 8; ++j)
            atomicAdd(&vs[row * D_DIM + dg + 32 * j], oacc[i][j]);
    }
}

// ---------------------------------------------------------------------------
extern "C" void kernel_launch(void* const* d_in, const int* in_sizes, int n_in,
                              void* d_out, int out_size, void* d_ws, size_t ws_size,
                              hipStream_t stream)
{
    const float* query = (const float*)d_in[0];
    const float* key   = (const float*)d_in[1];
    const float* value = (const float*)d_in[2];
    const float* Wk  = (const float*)d_in[3];
    const float* bk  = (const float*)d_in[4];
    const float* Wq  = (const float*)d_in[5];
    const float* bq  = (const float*)d_in[6];
    const float* Wva = (const float*)d_in[7];
    const float* bva = (const float*)d_in[8];
    const float* Wl  = (const float*)d_in[9];
    const float* bl  = (const float*)d_in[10];
    const float* Wvo = (const float*)d_in[11];
    const float* bvo = (const float*)d_in[12];

    const int MAT = S_LEN * D_DIM;           // 131072 floats
    float* ws   = (float*)d_ws;
    float* kbuf = ws;
    float* qbuf = ws + MAT;
    float* vbuf = ws + 2 * MAT;
    float* mbuf = ws + 3 * MAT;
    float* sbuf = ws + 4 * MAT;
    float* vs   = ws + 5 * MAT;
    float* out  = (float*)d_out;

    // K1: token linears (residual)
    linres_kernel<<<64, 256, 0, stream>>>(key,   Wk,  bk,  kbuf);
    linres_kernel<<<64, 256, 0, stream>>>(query, Wq,  bq,  qbuf);
    linres_kernel<<<64, 256, 0, stream>>>(value, Wva, bva, vbuf);

    // zero value_sum accumulator (ws is poisoned 0xAA each call)
    hipMemsetAsync(vs, 0, MAT * sizeof(float), stream);

    // K2: swishmax stats per (sk,d)
    stats_kernel<<<512, 256, 0, stream>>>(qbuf, kbuf, Wl, bl, mbuf, sbuf);

    // K3: weighted accumulation over sk
    accum_kernel<<<dim3(8, 64), 256, 0, stream>>>(qbuf, kbuf, vbuf, Wl, bl,
                                                  mbuf, sbuf, vs);

    // K4: output linear
    linres_kernel<<<64, 256, 0, stream>>>(vs, Wvo, bvo, out);
}

// Round 2
// 395.308 us; speedup vs baseline: 4.1317x; 4.1317x over previous
//
#include <hip/hip_runtime.h>
#include <math.h>

#define S_LEN 512
#define D_DIM 256
#define A_PITCH 264   // 64-row fp16 A tile, pitch 264 halfs = 528 B (16B-aligned, 2-way LDS conflicts = free)

typedef _Float16 half8 __attribute__((ext_vector_type(8)));
typedef float floatx4 __attribute__((ext_vector_type(4)));

// ---------------------------------------------------------------------------
// Prep: WlhT[d][e] = fp16(Wl[e][d] + (e==d))   (raw + raw@Wl == raw@(I+Wl))
// Transposed so the MFMA B fragment (lane n=l&15 reads 8 contiguous k) is a
// single 16-byte global load from L2.
// ---------------------------------------------------------------------------
__global__ __launch_bounds__(256) void prep_wl(const float* __restrict__ Wl,
                                               _Float16* __restrict__ WlhT)
{
    const int d = blockIdx.x;
    const int e = threadIdx.x;
    float v = Wl[e * D_DIM + d] + (e == d ? 1.0f : 0.0f);
    WlhT[d * D_DIM + e] = (_Float16)v;
}

// ---------------------------------------------------------------------------
// K1/K4: y = x + x@W + b   for [512,256]@[256,256]. 8 rows per block. (fp32)
// ---------------------------------------------------------------------------
__global__ __launch_bounds__(256) void linres_kernel(
    const float* __restrict__ x, const float* __restrict__ W,
    const float* __restrict__ b, float* __restrict__ y)
{
    __shared__ float xs[8][D_DIM];
    const int tid = threadIdx.x;
    const int r0 = blockIdx.x * 8;

    #pragma unroll
    for (int t = 0; t < 8; ++t)
        xs[t][tid] = x[(r0 + t) * D_DIM + tid];
    __syncthreads();

    float acc[8];
    const float bv = b[tid];
    #pragma unroll
    for (int i = 0; i < 8; ++i)
        acc[i] = xs[i][tid] + bv;

    #pragma unroll 4
    for (int e = 0; e < D_DIM; ++e) {
        const float w = W[e * D_DIM + tid];
        #pragma unroll
        for (int i = 0; i < 8; ++i)
            acc[i] += xs[i][e] * w;
    }
    #pragma unroll
    for (int i = 0; i < 8; ++i)
        y[(r0 + i) * D_DIM + tid] = acc[i];
}

// ---------------------------------------------------------------------------
// Stage Ah[i][e] = fp16(q[sq0+i][e] * k_sh[e]), 64x256 tile, 64 elems/thread.
// ---------------------------------------------------------------------------
__device__ __forceinline__ void stage_A(const float* __restrict__ qbuf,
                                        const float* k_sh,
                                        _Float16 (*Ah)[A_PITCH],
                                        int sq0, int tid)
{
    const int i  = tid >> 2;
    const int c0 = (tid & 3) * 64;
    const float* qrow = qbuf + (size_t)(sq0 + i) * D_DIM + c0;
    const float* krow = k_sh + c0;
    #pragma unroll
    for (int u = 0; u < 8; ++u) {
        float4 q0 = *(const float4*)(qrow + 8 * u);
        float4 q1 = *(const float4*)(qrow + 8 * u + 4);
        float4 k0 = *(const float4*)(krow + 8 * u);
        float4 k1 = *(const float4*)(krow + 8 * u + 4);
        half8 h;
        h[0] = (_Float16)(q0.x * k0.x); h[1] = (_Float16)(q0.y * k0.y);
        h[2] = (_Float16)(q0.z * k0.z); h[3] = (_Float16)(q0.w * k0.w);
        h[4] = (_Float16)(q1.x * k1.x); h[5] = (_Float16)(q1.y * k1.y);
        h[6] = (_Float16)(q1.z * k1.z); h[7] = (_Float16)(q1.w * k1.w);
        *(half8*)&Ah[i][c0 + 8 * u] = h;
    }
}

// ---------------------------------------------------------------------------
// K2: per-sk swishmax stats via MFMA. One block per sk; 4 waves x 64d strips;
// sq loop 8x64. m[sk,d] = max_sq L, S[sk,d] = sum_sq |L| exp(L-m).
// ---------------------------------------------------------------------------
__global__ __launch_bounds__(256) void stats_mfma(
    const float* __restrict__ qbuf, const float* __restrict__ kbuf,
    const _Float16* __restrict__ WlhT, const float* __restrict__ bl,
    float* __restrict__ mbuf, float* __restrict__ sbuf)
{
    __shared__ _Float16 Ah[64][A_PITCH];
    __shared__ float k_sh[D_DIM];

    const int tid  = threadIdx.x;
    const int lane = tid & 63, wave = tid >> 6;
    const int quad = lane >> 4, l16 = lane & 15;
    const int sk   = blockIdx.x;

    k_sh[tid] = kbuf[sk * D_DIM + tid];

    float bl_r[4];
    #pragma unroll
    for (int nt = 0; nt < 4; ++nt)
        bl_r[nt] = bl[wave * 64 + nt * 16 + l16];

    float m_run[4], S_run[4];
    #pragma unroll
    for (int nt = 0; nt < 4; ++nt) { m_run[nt] = -1e30f; S_run[nt] = 0.f; }

    for (int t = 0; t < 8; ++t) {
        const int sq0 = t * 64;
        __syncthreads();
        stage_A(qbuf, k_sh, Ah, sq0, tid);
        __syncthreads();

        floatx4 acc[4][4];
        #pragma unroll
        for (int mt = 0; mt < 4; ++mt)
            #pragma unroll
            for (int nt = 0; nt < 4; ++nt)
                acc[mt][nt] = (floatx4){0.f, 0.f, 0.f, 0.f};

        #pragma unroll 2
        for (int kk = 0; kk < 8; ++kk) {
            const int e0 = kk * 32;
            half8 af[4], bf[4];
            #pragma unroll
            for (int mt = 0; mt < 4; ++mt)
                af[mt] = *(const half8*)&Ah[mt * 16 + l16][e0 + quad * 8];
            #pragma unroll
            for (int nt = 0; nt < 4; ++nt)
                bf[nt] = *(const half8*)(WlhT +
                          (size_t)(wave * 64 + nt * 16 + l16) * D_DIM + e0 + quad * 8);
            #pragma unroll
            for (int mt = 0; mt < 4; ++mt)
                #pragma unroll
                for (int nt = 0; nt < 4; ++nt)
                    acc[mt][nt] = __builtin_amdgcn_mfma_f32_16x16x32_f16(
                        af[mt], bf[nt], acc[mt][nt], 0, 0, 0);
        }

        // online max / abs-exp-sum over this 64-sq tile (rows live in regs)
        #pragma unroll
        for (int nt = 0; nt < 4; ++nt) {
            float Lv[4][4];
            float tmax = -1e30f;
            #pragma unroll
            for (int mt = 0; mt < 4; ++mt)
                #pragma unroll
                for (int r = 0; r < 4; ++r) {
                    float L = acc[mt][nt][r] + bl_r[nt];
                    Lv[mt][r] = L;
                    tmax = fmaxf(tmax, L);
                }
            const float nm = fmaxf(m_run[nt], tmax);
            float s = S_run[nt] * __expf(m_run[nt] - nm);
            #pragma unroll
            for (int mt = 0; mt < 4; ++mt)
                #pragma unroll
                for (int r = 0; r < 4; ++r)
                    s += fabsf(Lv[mt][r]) * __expf(Lv[mt][r] - nm);
            m_run[nt] = nm;
            S_run[nt] = s;
        }
    }

    // reduce across the 4 quads that share a column (lanes l, l^16, l^32, l^48)
    #pragma unroll
    for (int nt = 0; nt < 4; ++nt) {
        float m = m_run[nt], s = S_run[nt];
        #pragma unroll
        for (int mask = 16; mask <= 32; mask <<= 1) {
            float m2 = __shfl_xor(m, mask, 64);
            float s2 = __shfl_xor(s, mask, 64);
            float M  = fmaxf(m, m2);
            s = s * __expf(m - M) + s2 * __expf(m2 - M);
            m = M;
        }
        m_run[nt] = m; S_run[nt] = s;
    }
    if (quad == 0) {
        #pragma unroll
        for (int nt = 0; nt < 4; ++nt) {
            const int d = wave * 64 + nt * 16 + l16;
            mbuf[sk * D_DIM + d] = m_run[nt];
            sbuf[sk * D_DIM + d] = S_run[nt];
        }
    }
}

// ---------------------------------------------------------------------------
// K3: recompute L via MFMA, apply swishmax scale, accumulate over 8 sk in
// registers, one atomicAdd per element at the end.
// Grid: (8 sq-tiles, 64 sk-groups).
// ---------------------------------------------------------------------------
__global__ __launch_bounds__(256) void accum_mfma(
    const float* __restrict__ qbuf, const float* __restrict__ kbuf,
    const float* __restrict__ vbuf, const _Float16* __restrict__ WlhT,
    const float* __restrict__ bl, const float* __restrict__ mbuf,
    const float* __restrict__ sbuf, float* __restrict__ vs)
{
    __shared__ _Float16 Ah[64][A_PITCH];
    __shared__ float k_sh[D_DIM];

    const int tid  = threadIdx.x;
    const int lane = tid & 63, wave = tid >> 6;
    const int quad = lane >> 4, l16 = lane & 15;
    const int sq0  = blockIdx.x * 64;
    const int sk0  = blockIdx.y * 8;

    float bl_r[4];
    #pragma unroll
    for (int nt = 0; nt < 4; ++nt)
        bl_r[nt] = bl[wave * 64 + nt * 16 + l16];

    floatx4 o[4][4];
    #pragma unroll
    for (int mt = 0; mt < 4; ++mt)
        #pragma unroll
        for (int nt = 0; nt < 4; ++nt)
            o[mt][nt] = (floatx4){0.f, 0.f, 0.f, 0.f};

    for (int s = 0; s < 8; ++s) {
        const int sk = sk0 + s;
        __syncthreads();
        k_sh[tid] = kbuf[sk * D_DIM + tid];
        __syncthreads();
        stage_A(qbuf, k_sh, Ah, sq0, tid);
        __syncthreads();

        float m_r[4], inv_r[4], v_r[4];
        #pragma unroll
        for (int nt = 0; nt < 4; ++nt) {
            const int d = wave * 64 + nt * 16 + l16;
            m_r[nt]   = mbuf[sk * D_DIM + d];
            inv_r[nt] = 1.0f / (sbuf[sk * D_DIM + d] + 1.0f);
            v_r[nt]   = vbuf[sk * D_DIM + d];
        }

        floatx4 acc[4][4];
        #pragma unroll
        for (int mt = 0; mt < 4; ++mt)
            #pragma unroll
            for (int nt = 0; nt < 4; ++nt)
                acc[mt][nt] = (floatx4){0.f, 0.f, 0.f, 0.f};

        #pragma unroll 2
        for (int kk = 0; kk < 8; ++kk) {
            const int e0 = kk * 32;
            half8 af[4], bf[4];
            #pragma unroll
            for (int mt = 0; mt < 4; ++mt)
                af[mt] = *(const half8*)&Ah[mt * 16 + l16][e0 + quad * 8];
            #pragma unroll
            for (int nt = 0; nt < 4; ++nt)
                bf[nt] = *(const half8*)(WlhT +
                          (size_t)(wave * 64 + nt * 16 + l16) * D_DIM + e0 + quad * 8);
            #pragma unroll
            for (int mt = 0; mt < 4; ++mt)
                #pragma unroll
                for (int nt = 0; nt < 4; ++nt)
                    acc[mt][nt] = __builtin_amdgcn_mfma_f32_16x16x32_f16(
                        af[mt], bf[nt], acc[mt][nt], 0, 0, 0);
        }

        #pragma unroll
        for (int nt = 0; nt < 4; ++nt)
            #pragma unroll
            for (int mt = 0; mt < 4; ++mt)
                #pragma unroll
                for (int r = 0; r < 4; ++r) {
                    const float L = acc[mt][nt][r] + bl_r[nt];
                    const float p = L * __expf(L - m_r[nt]) * inv_r[nt];
                    o[mt][nt][r] += v_r[nt] * p;
                }
    }

    #pragma unroll
    for (int mt = 0; mt < 4; ++mt)
        #pragma unroll
        for (int nt = 0; nt < 4; ++nt)
            #pragma unroll
            for (int r = 0; r < 4; ++r) {
                const int row = sq0 + mt * 16 + quad * 4 + r;
                const int col = wave * 64 + nt * 16 + l16;
                atomicAdd(&vs[row * D_DIM + col], o[mt][nt][r]);
            }
}

// ---------------------------------------------------------------------------
extern "C" void kernel_launch(void* const* d_in, const int* in_sizes, int n_in,
                              void* d_out, int out_size, void* d_ws, size_t ws_size,
                              hipStream_t stream)
{
    const float* query = (const float*)d_in[0];
    const float* key   = (const float*)d_in[1];
    const float* value = (const float*)d_in[2];
    const float* Wk  = (const float*)d_in[3];
    const float* bk  = (const float*)d_in[4];
    const float* Wq  = (const float*)d_in[5];
    const float* bq  = (const float*)d_in[6];
    const float* Wva = (const float*)d_in[7];
    const float* bva = (const float*)d_in[8];
    const float* Wl  = (const float*)d_in[9];
    const float* bl  = (const float*)d_in[10];
    const float* Wvo = (const float*)d_in[11];
    const float* bvo = (const float*)d_in[12];

    const int MAT = S_LEN * D_DIM;           // 131072 floats
    float* ws   = (float*)d_ws;
    float* kbuf = ws;
    float* qbuf = ws + MAT;
    float* vbuf = ws + 2 * MAT;
    float* mbuf = ws + 3 * MAT;
    float* sbuf = ws + 4 * MAT;
    float* vs   = ws + 5 * MAT;
    _Float16* WlhT = (_Float16*)(ws + 6 * MAT);   // 256x256 fp16 = 128 KB
    float* out  = (float*)d_out;

    // prep: token linears + (I+Wl)^T fp16
    prep_wl<<<256, 256, 0, stream>>>(Wl, WlhT);
    linres_kernel<<<64, 256, 0, stream>>>(key,   Wk,  bk,  kbuf);
    linres_kernel<<<64, 256, 0, stream>>>(query, Wq,  bq,  qbuf);
    linres_kernel<<<64, 256, 0, stream>>>(value, Wva, bva, vbuf);

    hipMemsetAsync(vs, 0, MAT * sizeof(float), stream);

    stats_mfma<<<512, 256, 0, stream>>>(qbuf, kbuf, WlhT, bl, mbuf, sbuf);
    accum_mfma<<<dim3(8, 64), 256, 0, stream>>>(qbuf, kbuf, vbuf, WlhT, bl,
                                                mbuf, sbuf, vs);

    linres_kernel<<<64, 256, 0, stream>>>(vs, Wvo, bvo, out);
}

// Round 3
// 376.842 us; speedup vs baseline: 4.3341x; 1.0490x over previous
//
#include <hip/hip_runtime.h>
#include <math.h>

#define S_LEN 512
#define D_DIM 256

typedef _Float16 half8  __attribute__((ext_vector_type(8)));
typedef _Float16 half4v __attribute__((ext_vector_type(4)));
typedef float   floatx4 __attribute__((ext_vector_type(4)));

// ---------------------------------------------------------------------------
// WlhT[d][e] = fp16(Wl[e][d] + (e==d))     (raw + raw@Wl == raw@(I+Wl))
// ---------------------------------------------------------------------------
__global__ __launch_bounds__(256) void prep_wl(const float* __restrict__ Wl,
                                               _Float16* __restrict__ WlhT)
{
    const int d = blockIdx.x, e = threadIdx.x;
    float v = Wl[e * D_DIM + d] + (e == d ? 1.0f : 0.0f);
    WlhT[d * D_DIM + e] = (_Float16)v;
}

// ---------------------------------------------------------------------------
// fp32 -> fp16 copies of k and q (post-linres)
// ---------------------------------------------------------------------------
__global__ __launch_bounds__(256) void cvt_fp16(const float* __restrict__ kf,
                                                const float* __restrict__ qf,
                                                _Float16* __restrict__ kh,
                                                _Float16* __restrict__ qh)
{
    const int i = (blockIdx.x * 256 + threadIdx.x) * 4;
    float4 a = *(const float4*)(kf + i);
    float4 b = *(const float4*)(qf + i);
    half4v ah = { (_Float16)a.x, (_Float16)a.y, (_Float16)a.z, (_Float16)a.w };
    half4v bh = { (_Float16)b.x, (_Float16)b.y, (_Float16)b.z, (_Float16)b.w };
    *(half4v*)(kh + i) = ah;
    *(half4v*)(qh + i) = bh;
}

// ---------------------------------------------------------------------------
// y = x + x@W + b  for [512,256]@[256,256]; 4 rows per block (fp32, small).
// ---------------------------------------------------------------------------
__device__ __forceinline__ void linres_body(const float* __restrict__ x,
                                            const float* __restrict__ W,
                                            const float* __restrict__ b,
                                            float* __restrict__ y, int r0)
{
    __shared__ float xs[4][D_DIM];
    const int tid = threadIdx.x;
    #pragma unroll
    for (int t = 0; t < 4; ++t) xs[t][tid] = x[(r0 + t) * D_DIM + tid];
    __syncthreads();
    const float bv = b[tid];
    float acc[4];
    #pragma unroll
    for (int i = 0; i < 4; ++i) acc[i] = xs[i][tid] + bv;
    #pragma unroll 4
    for (int e = 0; e < D_DIM; ++e) {
        const float w = W[e * D_DIM + tid];
        #pragma unroll
        for (int i = 0; i < 4; ++i) acc[i] += xs[i][e] * w;
    }
    #pragma unroll
    for (int i = 0; i < 4; ++i) y[(r0 + i) * D_DIM + tid] = acc[i];
}

__global__ __launch_bounds__(256) void linres3(
    const float* __restrict__ xk, const float* __restrict__ Wk,
    const float* __restrict__ bk, float* __restrict__ yk,
    const float* __restrict__ xq, const float* __restrict__ Wq,
    const float* __restrict__ bq, float* __restrict__ yq,
    const float* __restrict__ xv, const float* __restrict__ Wv,
    const float* __restrict__ bv, float* __restrict__ yv)
{
    const int r0 = blockIdx.x * 4;
    const int sel = blockIdx.y;
    const float* x = sel == 0 ? xk : (sel == 1 ? xq : xv);
    const float* W = sel == 0 ? Wk : (sel == 1 ? Wq : Wv);
    const float* b = sel == 0 ? bk : (sel == 1 ? bq : bv);
    float*       y = sel == 0 ? yk : (sel == 1 ? yq : yv);
    linres_body(x, W, b, y, r0);
}

__global__ __launch_bounds__(256) void linres1(
    const float* __restrict__ x, const float* __restrict__ W,
    const float* __restrict__ b, float* __restrict__ y)
{
    linres_body(x, W, b, y, blockIdx.x * 4);
}

// ---------------------------------------------------------------------------
// Stage 64x256 fp16 q tile into fragment-major LDS:
// fragment block fb = mt*8+kk (mt=row/16, kk=e/32); lane slot = quad*16+l16
// (quad=(e>>3)&3, l16=row&15); addr16 = fb*64 + slot. Reads are lane-
// contiguous b128 => conflict-free; writes: 8 consecutive tids hit 8
// distinct (addr16 mod 8) => conflict-free.
// ---------------------------------------------------------------------------
__device__ __forceinline__ void stage_q(const _Float16* __restrict__ qh,
                                        _Float16* __restrict__ Afrag,
                                        int sq0, int tid)
{
    const int i   = tid & 63;   // row within tile
    const int qtr = tid >> 6;   // e-quarter (64 elems)
    const int mt = i >> 4, l16 = i & 15;
    const half8* src = (const half8*)(qh + (size_t)(sq0 + i) * D_DIM + qtr * 64);
    #pragma unroll
    for (int u = 0; u < 8; ++u) {
        const int eb   = qtr * 8 + u;           // e-block (8 halfs) 0..31
        const int kk   = eb >> 2, quad = eb & 3;
        const int addr16 = (mt * 8 + kk) * 64 + quad * 16 + l16;
        *(half8*)(Afrag + addr16 * 8) = src[u];
    }
}

// ---------------------------------------------------------------------------
// Stats: L = q @ (diag(k_sk)(I+Wl)) + bl per sk; per-(sk,d) tile-partial
// (max, sum |L| e^(L-max)) over this block's 64 sq rows -> pm/ps.
// Grid (8 sq-tiles, 64 sk-chunks of 8). ONE barrier per block.
// ---------------------------------------------------------------------------
__global__ __launch_bounds__(256) void stats_mfma(
    const _Float16* __restrict__ qh, const _Float16* __restrict__ kh,
    const _Float16* __restrict__ WlhT, const float* __restrict__ bl,
    float* __restrict__ pm, float* __restrict__ ps)
{
    __shared__ _Float16 Afrag[32 * 64 * 8];   // 32 KB

    const int tid  = threadIdx.x;
    const int lane = tid & 63, wave = tid >> 6;
    const int quad = lane >> 4, l16 = lane & 15;
    const int sqt  = blockIdx.x, sq0 = sqt * 64;
    const int sk0  = blockIdx.y * 8;

    stage_q(qh, Afrag, sq0, tid);

    half8 wl[4][8];
    #pragma unroll
    for (int nt = 0; nt < 4; ++nt) {
        const int d = wave * 64 + nt * 16 + l16;
        #pragma unroll
        for (int kk = 0; kk < 8; ++kk)
            wl[nt][kk] = *(const half8*)(WlhT + (size_t)d * D_DIM + kk * 32 + quad * 8);
    }
    float bl_r[4];
    #pragma unroll
    for (int nt = 0; nt < 4; ++nt)
        bl_r[nt] = bl[wave * 64 + nt * 16 + l16];

    __syncthreads();

    #pragma unroll 1
    for (int s = 0; s < 8; ++s) {
        const int sk = sk0 + s;
        floatx4 acc[4][4];
        #pragma unroll
        for (int mt = 0; mt < 4; ++mt)
            #pragma unroll
            for (int nt = 0; nt < 4; ++nt)
                acc[mt][nt] = (floatx4){0.f, 0.f, 0.f, 0.f};

        #pragma unroll 2
        for (int kk = 0; kk < 8; ++kk) {
            const half8 k8 = *(const half8*)(kh + (size_t)sk * D_DIM + kk * 32 + quad * 8);
            half8 af[4], bf[4];
            #pragma unroll
            for (int mt = 0; mt < 4; ++mt)
                af[mt] = *(const half8*)(Afrag + ((mt * 8 + kk) * 64 + lane) * 8);
            #pragma unroll
            for (int nt = 0; nt < 4; ++nt)
                bf[nt] = wl[nt][kk] * k8;
            #pragma unroll
            for (int mt = 0; mt < 4; ++mt)
                #pragma unroll
                for (int nt = 0; nt < 4; ++nt)
                    acc[mt][nt] = __builtin_amdgcn_mfma_f32_16x16x32_f16(
                        af[mt], bf[nt], acc[mt][nt], 0, 0, 0);
        }

        #pragma unroll
        for (int nt = 0; nt < 4; ++nt) {
            float Lv[4][4];
            float tmax = -1e30f;
            #pragma unroll
            for (int mt = 0; mt < 4; ++mt)
                #pragma unroll
                for (int r = 0; r < 4; ++r) {
                    const float L = acc[mt][nt][r] + bl_r[nt];
                    Lv[mt][r] = L;
                    tmax = fmaxf(tmax, L);
                }
            float tsum = 0.f;
            #pragma unroll
            for (int mt = 0; mt < 4; ++mt)
                #pragma unroll
                for (int r = 0; r < 4; ++r)
                    tsum += fabsf(Lv[mt][r]) * __expf(Lv[mt][r] - tmax);

            float m = tmax, ss = tsum;
            #pragma unroll
            for (int mask = 16; mask <= 32; mask <<= 1) {
                float m2 = __shfl_xor(m, mask, 64);
                float s2 = __shfl_xor(ss, mask, 64);
                float M  = fmaxf(m, m2);
                ss = ss * __expf(m - M) + s2 * __expf(m2 - M);
                m = M;
            }
            if (quad == 0) {
                const int d = wave * 64 + nt * 16 + l16;
                pm[((size_t)sqt * S_LEN + sk) * D_DIM + d] = m;
                ps[((size_t)sqt * S_LEN + sk) * D_DIM + d] = ss;
            }
        }
    }
}

// ---------------------------------------------------------------------------
// Merge the 8 sq-tile partials -> mbuf, sbuf
// ---------------------------------------------------------------------------
__global__ __launch_bounds__(256) void reduce_ms(
    const float* __restrict__ pm, const float* __restrict__ ps,
    float* __restrict__ mbuf, float* __restrict__ sbuf)
{
    const int idx = blockIdx.x * 256 + threadIdx.x;   // (sk,d), 131072 total
    float m = pm[idx], ss = ps[idx];
    #pragma unroll
    for (int t = 1; t < 8; ++t) {
        const float m2 = pm[t * (S_LEN * D_DIM) + idx];
        const float s2 = ps[t * (S_LEN * D_DIM) + idx];
        const float M  = fmaxf(m, m2);
        ss = ss * __expf(m - M) + s2 * __expf(m2 - M);
        m = M;
    }
    mbuf[idx] = m;
    sbuf[idx] = ss;
}

// ---------------------------------------------------------------------------
// Accum: recompute L, p = L e^(L-m) / (S+1); o += v[sk,d]*p over sk;
// one atomicAdd per element. Grid (8 sq-tiles, 64 sk-chunks of 8).
// ---------------------------------------------------------------------------
__global__ __launch_bounds__(256) void accum_mfma(
    const _Float16* __restrict__ qh, const _Float16* __restrict__ kh,
    const _Float16* __restrict__ WlhT, const float* __restrict__ bl,
    const float* __restrict__ mbuf, const float* __restrict__ sbuf,
    const float* __restrict__ vbuf, float* __restrict__ vs)
{
    __shared__ _Float16 Afrag[32 * 64 * 8];   // 32 KB

    const int tid  = threadIdx.x;
    const int lane = tid & 63, wave = tid >> 6;
    const int quad = lane >> 4, l16 = lane & 15;
    const int sq0  = blockIdx.x * 64;
    const int sk0  = blockIdx.y * 8;

    stage_q(qh, Afrag, sq0, tid);

    half8 wl[4][8];
    #pragma unroll
    for (int nt = 0; nt < 4; ++nt) {
        const int d = wave * 64 + nt * 16 + l16;
        #pragma unroll
        for (int kk = 0; kk < 8; ++kk)
            wl[nt][kk] = *(const half8*)(WlhT + (size_t)d * D_DIM + kk * 32 + quad * 8);
    }
    float bl_r[4];
    #pragma unroll
    for (int nt = 0; nt < 4; ++nt)
        bl_r[nt] = bl[wave * 64 + nt * 16 + l16];

    floatx4 o[4][4];
    #pragma unroll
    for (int mt = 0; mt < 4; ++mt)
        #pragma unroll
        for (int nt = 0; nt < 4; ++nt)
            o[mt][nt] = (floatx4){0.f, 0.f, 0.f, 0.f};

    __syncthreads();

    #pragma unroll 1
    for (int s = 0; s < 8; ++s) {
        const int sk = sk0 + s;
        floatx4 acc[4][4];
        #pragma unroll
        for (int mt = 0; mt < 4; ++mt)
            #pragma unroll
            for (int nt = 0; nt < 4; ++nt)
                acc[mt][nt] = (floatx4){0.f, 0.f, 0.f, 0.f};

        #pragma unroll 2
        for (int kk = 0; kk < 8; ++kk) {
            const half8 k8 = *(const half8*)(kh + (size_t)sk * D_DIM + kk * 32 + quad * 8);
            half8 af[4], bf[4];
            #pragma unroll
            for (int mt = 0; mt < 4; ++mt)
                af[mt] = *(const half8*)(Afrag + ((mt * 8 + kk) * 64 + lane) * 8);
            #pragma unroll
            for (int nt = 0; nt < 4; ++nt)
                bf[nt] = wl[nt][kk] * k8;
            #pragma unroll
            for (int mt = 0; mt < 4; ++mt)
                #pragma unroll
                for (int nt = 0; nt < 4; ++nt)
                    acc[mt][nt] = __builtin_amdgcn_mfma_f32_16x16x32_f16(
                        af[mt], bf[nt], acc[mt][nt], 0, 0, 0);
        }

        #pragma unroll
        for (int nt = 0; nt < 4; ++nt) {
            const int d = wave * 64 + nt * 16 + l16;
            const float m_r = mbuf[(size_t)sk * D_DIM + d];
            const float inv = 1.0f / (sbuf[(size_t)sk * D_DIM + d] + 1.0f);
            const float vv  = vbuf[(size_t)sk * D_DIM + d];
            #pragma unroll
            for (int mt = 0; mt < 4; ++mt)
                #pragma unroll
                for (int r = 0; r < 4; ++r) {
                    const float L = acc[mt][nt][r] + bl_r[nt];
                    const float p = L * __expf(L - m_r) * inv;
                    o[mt][nt][r] += vv * p;
                }
        }
    }

    #pragma unroll
    for (int mt = 0; mt < 4; ++mt)
        #pragma unroll
        for (int nt = 0; nt < 4; ++nt)
            #pragma unroll
            for (int r = 0; r < 4; ++r) {
                const int row = sq0 + mt * 16 + quad * 4 + r;
                const int col = wave * 64 + nt * 16 + l16;
                atomicAdd(&vs[(size_t)row * D_DIM + col], o[mt][nt][r]);
            }
}

// ---------------------------------------------------------------------------
extern "C" void kernel_launch(void* const* d_in, const int* in_sizes, int n_in,
                              void* d_out, int out_size, void* d_ws, size_t ws_size,
                              hipStream_t stream)
{
    const float* query = (const float*)d_in[0];
    const float* key   = (const float*)d_in[1];
    const float* value = (const float*)d_in[2];
    const float* Wk  = (const float*)d_in[3];
    const float* bk  = (const float*)d_in[4];
    const float* Wq  = (const float*)d_in[5];
    const float* bq  = (const float*)d_in[6];
    const float* Wva = (const float*)d_in[7];
    const float* bva = (const float*)d_in[8];
    const float* Wl  = (const float*)d_in[9];
    const float* bl  = (const float*)d_in[10];
    const float* Wvo = (const float*)d_in[11];
    const float* bvo = (const float*)d_in[12];

    const int MAT = S_LEN * D_DIM;            // 131072
    float* ws   = (float*)d_ws;
    float* kbuf = ws;
    float* qbuf = ws + MAT;
    float* vbuf = ws + 2 * MAT;
    float* mbuf = ws + 3 * MAT;
    float* sbuf = ws + 4 * MAT;
    float* vs   = ws + 5 * MAT;
    _Float16* WlhT = (_Float16*)(ws + 6 * MAT);            // 128 KB
    _Float16* kh   = (_Float16*)(ws + 6 * MAT + 32768);    // 256 KB
    _Float16* qh   = kh + MAT;                             // 256 KB
    float* pm  = ws + 6 * MAT + 32768 + 2 * 65536;         // 4 MB
    float* ps  = pm + 8 * MAT;                             // 4 MB
    float* out = (float*)d_out;

    prep_wl<<<256, 256, 0, stream>>>(Wl, WlhT);
    linres3<<<dim3(128, 3), 256, 0, stream>>>(key, Wk, bk, kbuf,
                                              query, Wq, bq, qbuf,
                                              value, Wva, bva, vbuf);
    cvt_fp16<<<128, 256, 0, stream>>>(kbuf, qbuf, kh, qh);
    hipMemsetAsync(vs, 0, MAT * sizeof(float), stream);

    stats_mfma<<<dim3(8, 64), 256, 0, stream>>>(qh, kh, WlhT, bl, pm, ps);
    reduce_ms<<<512, 256, 0, stream>>>(pm, ps, mbuf, sbuf);
    accum_mfma<<<dim3(8, 64), 256, 0, stream>>>(qh, kh, WlhT, bl,
                                                mbuf, sbuf, vbuf, vs);

    linres1<<<128, 256, 0, stream>>>(vs, Wvo, bvo, out);
}

// Round 7
// 326.974 us; speedup vs baseline: 4.9952x; 1.1525x over previous
//
#include <hip/hip_runtime.h>
#include <math.h>

#define S_LEN 512
#define D_DIM 256

typedef _Float16 half8  __attribute__((ext_vector_type(8)));
typedef _Float16 half4v __attribute__((ext_vector_type(4)));
typedef float   floatx4 __attribute__((ext_vector_type(4)));

// ---------------------------------------------------------------------------
// WlhT[d][e] = fp16(Wl[e][d] + (e==d))     (raw + raw@Wl == raw@(I+Wl))
// ---------------------------------------------------------------------------
__global__ __launch_bounds__(256) void prep_wl(const float* __restrict__ Wl,
                                               _Float16* __restrict__ WlhT)
{
    const int d = blockIdx.x, e = threadIdx.x;
    float v = Wl[e * D_DIM + d] + (e == d ? 1.0f : 0.0f);
    WlhT[d * D_DIM + e] = (_Float16)v;
}

// ---------------------------------------------------------------------------
// fp32 -> fp16 copies of k and q (post-linres)
// ---------------------------------------------------------------------------
__global__ __launch_bounds__(256) void cvt_fp16(const float* __restrict__ kf,
                                                const float* __restrict__ qf,
                                                _Float16* __restrict__ kh,
                                                _Float16* __restrict__ qh)
{
    const int i = (blockIdx.x * 256 + threadIdx.x) * 4;
    float4 a = *(const float4*)(kf + i);
    float4 b = *(const float4*)(qf + i);
    half4v ah = { (_Float16)a.x, (_Float16)a.y, (_Float16)a.z, (_Float16)a.w };
    half4v bh = { (_Float16)b.x, (_Float16)b.y, (_Float16)b.z, (_Float16)b.w };
    *(half4v*)(kh + i) = ah;
    *(half4v*)(qh + i) = bh;
}

// ---------------------------------------------------------------------------
// y = x + x@W + b  for [512,256]@[256,256]; 4 rows per block (fp32, small).
// ---------------------------------------------------------------------------
__device__ __forceinline__ void linres_body(const float* __restrict__ x,
                                            const float* __restrict__ W,
                                            const float* __restrict__ b,
                                            float* __restrict__ y, int r0)
{
    __shared__ float xs[4][D_DIM];
    const int tid = threadIdx.x;
    #pragma unroll
    for (int t = 0; t < 4; ++t) xs[t][tid] = x[(r0 + t) * D_DIM + tid];
    __syncthreads();
    const float bv = b[tid];
    float acc[4];
    #pragma unroll
    for (int i = 0; i < 4; ++i) acc[i] = xs[i][tid] + bv;
    #pragma unroll 4
    for (int e = 0; e < D_DIM; ++e) {
        const float w = W[e * D_DIM + tid];
        #pragma unroll
        for (int i = 0; i < 4; ++i) acc[i] += xs[i][e] * w;
    }
    #pragma unroll
    for (int i = 0; i < 4; ++i) y[(r0 + i) * D_DIM + tid] = acc[i];
}

__global__ __launch_bounds__(256) void linres3(
    const float* __restrict__ xk, const float* __restrict__ Wk,
    const float* __restrict__ bk, float* __restrict__ yk,
    const float* __restrict__ xq, const float* __restrict__ Wq,
    const float* __restrict__ bq, float* __restrict__ yq,
    const float* __restrict__ xv, const float* __restrict__ Wv,
    const float* __restrict__ bv, float* __restrict__ yv)
{
    const int r0 = blockIdx.x * 4;
    const int sel = blockIdx.y;
    const float* x = sel == 0 ? xk : (sel == 1 ? xq : xv);
    const float* W = sel == 0 ? Wk : (sel == 1 ? Wq : Wv);
    const float* b = sel == 0 ? bk : (sel == 1 ? bq : bv);
    float*       y = sel == 0 ? yk : (sel == 1 ? yq : yv);
    linres_body(x, W, b, y, r0);
}

__global__ __launch_bounds__(256) void linres1(
    const float* __restrict__ x, const float* __restrict__ W,
    const float* __restrict__ b, float* __restrict__ y)
{
    linres_body(x, W, b, y, blockIdx.x * 4);
}

// ---------------------------------------------------------------------------
// Stage 64x256 fp16 q tile into fragment-major LDS (verbatim from R3-pass):
// fb = mt*8+kk; slot = quad*16+l16; addr16 = fb*64 + slot. Conflict-free.
// ---------------------------------------------------------------------------
__device__ __forceinline__ void stage_q(const _Float16* __restrict__ qh,
                                        _Float16* __restrict__ Afrag,
                                        int sq0, int tid)
{
    const int i   = tid & 63;   // row within tile
    const int qtr = tid >> 6;   // e-quarter (64 elems)
    const int mt = i >> 4, l16 = i & 15;
    const half8* src = (const half8*)(qh + (size_t)(sq0 + i) * D_DIM + qtr * 64);
    #pragma unroll
    for (int u = 0; u < 8; ++u) {
        const int eb   = qtr * 8 + u;           // e-block (8 halfs) 0..31
        const int kk   = eb >> 2, quad = eb & 3;
        const int addr16 = (mt * 8 + kk) * 64 + quad * 16 + l16;
        *(half8*)(Afrag + addr16 * 8) = src[u];
    }
}

// ---------------------------------------------------------------------------
// Stats: L = q @ (diag(k_sk)(I+Wl)) + bl per sk; per-(sk,d) tile-partial
// (max, sum |L| e^(L-max)) over this block's 64 sq rows -> pm/ps.
// Grid (8 sq-tiles, 2 d-halves, 64 sk-chunks of 8). ONE barrier per block.
// nt=2 (d32/wave) so wl[2][8]=64 VGPRs -> no spills (R3's wl[4][8]=128 spilled).
// ---------------------------------------------------------------------------
__global__ __launch_bounds__(256, 2) void stats_mfma(
    const _Float16* __restrict__ qh, const _Float16* __restrict__ kh,
    const _Float16* __restrict__ WlhT, const float* __restrict__ bl,
    float* __restrict__ pm, float* __restrict__ ps)
{
    __shared__ _Float16 Afrag[32 * 64 * 8];   // 32 KB

    const int tid  = threadIdx.x;
    const int lane = tid & 63, wave = tid >> 6;
    const int quad = lane >> 4, l16 = lane & 15;
    const int sqt  = blockIdx.x, sq0 = sqt * 64;
    const int dw   = blockIdx.y * 128 + wave * 32;
    const int sk0  = blockIdx.z * 8;

    stage_q(qh, Afrag, sq0, tid);

    half8 wl[2][8];
    #pragma unroll
    for (int nt = 0; nt < 2; ++nt) {
        const int d = dw + nt * 16 + l16;
        #pragma unroll
        for (int kk = 0; kk < 8; ++kk)
            wl[nt][kk] = *(const half8*)(WlhT + (size_t)d * D_DIM + kk * 32 + quad * 8);
    }
    float bl_r[2];
    #pragma unroll
    for (int nt = 0; nt < 2; ++nt)
        bl_r[nt] = bl[dw + nt * 16 + l16];

    __syncthreads();

    #pragma unroll 1
    for (int s = 0; s < 8; ++s) {
        const int sk = sk0 + s;
        floatx4 acc[4][2];
        #pragma unroll
        for (int mt = 0; mt < 4; ++mt)
            #pragma unroll
            for (int nt = 0; nt < 2; ++nt)
                acc[mt][nt] = (floatx4){0.f, 0.f, 0.f, 0.f};

        #pragma unroll 2
        for (int kk = 0; kk < 8; ++kk) {
            const half8 k8 = *(const half8*)(kh + (size_t)sk * D_DIM + kk * 32 + quad * 8);
            half8 af[4], bf[2];
            #pragma unroll
            for (int mt = 0; mt < 4; ++mt)
                af[mt] = *(const half8*)(Afrag + ((mt * 8 + kk) * 64 + lane) * 8);
            #pragma unroll
            for (int nt = 0; nt < 2; ++nt)
                bf[nt] = wl[nt][kk] * k8;
            #pragma unroll
            for (int mt = 0; mt < 4; ++mt)
                #pragma unroll
                for (int nt = 0; nt < 2; ++nt)
                    acc[mt][nt] = __builtin_amdgcn_mfma_f32_16x16x32_f16(
                        af[mt], bf[nt], acc[mt][nt], 0, 0, 0);
        }

        #pragma unroll
        for (int nt = 0; nt < 2; ++nt) {
            float Lv[4][4];
            float tmax = -1e30f;
            #pragma unroll
            for (int mt = 0; mt < 4; ++mt)
                #pragma unroll
                for (int r = 0; r < 4; ++r) {
                    const float L = acc[mt][nt][r] + bl_r[nt];
                    Lv[mt][r] = L;
                    tmax = fmaxf(tmax, L);
                }
            float tsum = 0.f;
            #pragma unroll
            for (int mt = 0; mt < 4; ++mt)
                #pragma unroll
                for (int r = 0; r < 4; ++r)
                    tsum += fabsf(Lv[mt][r]) * __expf(Lv[mt][r] - tmax);

            float m = tmax, ss = tsum;
            #pragma unroll
            for (int mask = 16; mask <= 32; mask <<= 1) {
                float m2 = __shfl_xor(m, mask, 64);
                float s2 = __shfl_xor(ss, mask, 64);
                float M  = fmaxf(m, m2);
                ss = ss * __expf(m - M) + s2 * __expf(m2 - M);
                m = M;
            }
            if (quad == 0) {
                const int d = dw + nt * 16 + l16;
                pm[((size_t)sqt * S_LEN + sk) * D_DIM + d] = m;
                ps[((size_t)sqt * S_LEN + sk) * D_DIM + d] = ss;
            }
        }
    }
}

// ---------------------------------------------------------------------------
// Merge the 8 sq-tile partials -> mbuf, sbuf  (verbatim from R3-pass)
// ---------------------------------------------------------------------------
__global__ __launch_bounds__(256) void reduce_ms(
    const float* __restrict__ pm, const float* __restrict__ ps,
    float* __restrict__ mbuf, float* __restrict__ sbuf)
{
    const int idx = blockIdx.x * 256 + threadIdx.x;   // (sk,d), 131072 total
    float m = pm[idx], ss = ps[idx];
    #pragma unroll
    for (int t = 1; t < 8; ++t) {
        const float m2 = pm[t * (S_LEN * D_DIM) + idx];
        const float s2 = ps[t * (S_LEN * D_DIM) + idx];
        const float M  = fmaxf(m, m2);
        ss = ss * __expf(m - M) + s2 * __expf(m2 - M);
        m = M;
    }
    mbuf[idx] = m;
    sbuf[idx] = ss;
}

// ---------------------------------------------------------------------------
// Accum: recompute L, p = L e^(L-m) / (S+1); o += v[sk,d]*p over sk;
// one atomicAdd per element. Grid (8 sq-tiles, 2 d-halves, 64 sk-chunks).
// ---------------------------------------------------------------------------
__global__ __launch_bounds__(256, 2) void accum_mfma(
    const _Float16* __restrict__ qh, const _Float16* __restrict__ kh,
    const _Float16* __restrict__ WlhT, const float* __restrict__ bl,
    const float* __restrict__ mbuf, const float* __restrict__ sbuf,
    const float* __restrict__ vbuf, float* __restrict__ vs)
{
    __shared__ _Float16 Afrag[32 * 64 * 8];   // 32 KB

    const int tid  = threadIdx.x;
    const int lane = tid & 63, wave = tid >> 6;
    const int quad = lane >> 4, l16 = lane & 15;
    const int sq0  = blockIdx.x * 64;
    const int dw   = blockIdx.y * 128 + wave * 32;
    const int sk0  = blockIdx.z * 8;

    stage_q(qh, Afrag, sq0, tid);

    half8 wl[2][8];
    #pragma unroll
    for (int nt = 0; nt < 2; ++nt) {
        const int d = dw + nt * 16 + l16;
        #pragma unroll
        for (int kk = 0; kk < 8; ++kk)
            wl[nt][kk] = *(const half8*)(WlhT + (size_t)d * D_DIM + kk * 32 + quad * 8);
    }
    float bl_r[2];
    #pragma unroll
    for (int nt = 0; nt < 2; ++nt)
        bl_r[nt] = bl[dw + nt * 16 + l16];

    floatx4 o[4][2];
    #pragma unroll
    for (int mt = 0; mt < 4; ++mt)
        #pragma unroll
        for (int nt = 0; nt < 2; ++nt)
            o[mt][nt] = (floatx4){0.f, 0.f, 0.f, 0.f};

    __syncthreads();

    #pragma unroll 1
    for (int s = 0; s < 8; ++s) {
        const int sk = sk0 + s;
        floatx4 acc[4][2];
        #pragma unroll
        for (int mt = 0; mt < 4; ++mt)
            #pragma unroll
            for (int nt = 0; nt < 2; ++nt)
                acc[mt][nt] = (floatx4){0.f, 0.f, 0.f, 0.f};

        #pragma unroll 2
        for (int kk = 0; kk < 8; ++kk) {
            const half8 k8 = *(const half8*)(kh + (size_t)sk * D_DIM + kk * 32 + quad * 8);
            half8 af[4], bf[2];
            #pragma unroll
            for (int mt = 0; mt < 4; ++mt)
                af[mt] = *(const half8*)(Afrag + ((mt * 8 + kk) * 64 + lane) * 8);
            #pragma unroll
            for (int nt = 0; nt < 2; ++nt)
                bf[nt] = wl[nt][kk] * k8;
            #pragma unroll
            for (int mt = 0; mt < 4; ++mt)
                #pragma unroll
                for (int nt = 0; nt < 2; ++nt)
                    acc[mt][nt] = __builtin_amdgcn_mfma_f32_16x16x32_f16(
                        af[mt], bf[nt], acc[mt][nt], 0, 0, 0);
        }

        #pragma unroll
        for (int nt = 0; nt < 2; ++nt) {
            const int d = dw + nt * 16 + l16;
            const float m_r = mbuf[(size_t)sk * D_DIM + d];
            const float inv = 1.0f / (sbuf[(size_t)sk * D_DIM + d] + 1.0f);
            const float vv  = vbuf[(size_t)sk * D_DIM + d];
            #pragma unroll
            for (int mt = 0; mt < 4; ++mt)
                #pragma unroll
                for (int r = 0; r < 4; ++r) {
                    const float L = acc[mt][nt][r] + bl_r[nt];
                    const float p = L * __expf(L - m_r) * inv;
                    o[mt][nt][r] += vv * p;
                }
        }
    }

    #pragma unroll
    for (int mt = 0; mt < 4; ++mt)
        #pragma unroll
        for (int nt = 0; nt < 2; ++nt)
            #pragma unroll
            for (int r = 0; r < 4; ++r) {
                const int row = sq0 + mt * 16 + quad * 4 + r;
                const int col = dw + nt * 16 + l16;
                atomicAdd(&vs[(size_t)row * D_DIM + col], o[mt][nt][r]);
            }
}

// ---------------------------------------------------------------------------
extern "C" void kernel_launch(void* const* d_in, const int* in_sizes, int n_in,
                              void* d_out, int out_size, void* d_ws, size_t ws_size,
                              hipStream_t stream)
{
    const float* query = (const float*)d_in[0];
    const float* key   = (const float*)d_in[1];
    const float* value = (const float*)d_in[2];
    const float* Wk  = (const float*)d_in[3];
    const float* bk  = (const float*)d_in[4];
    const float* Wq  = (const float*)d_in[5];
    const float* bq  = (const float*)d_in[6];
    const float* Wva = (const float*)d_in[7];
    const float* bva = (const float*)d_in[8];
    const float* Wl  = (const float*)d_in[9];
    const float* bl  = (const float*)d_in[10];
    const float* Wvo = (const float*)d_in[11];
    const float* bvo = (const float*)d_in[12];

    const int MAT = S_LEN * D_DIM;            // 131072
    float* ws   = (float*)d_ws;
    float* kbuf = ws;
    float* qbuf = ws + MAT;
    float* vbuf = ws + 2 * MAT;
    float* mbuf = ws + 3 * MAT;
    float* sbuf = ws + 4 * MAT;
    float* vs   = ws + 5 * MAT;
    _Float16* WlhT = (_Float16*)(ws + 6 * MAT);            // 128 KB
    _Float16* kh   = (_Float16*)(ws + 6 * MAT + 32768);    // 256 KB
    _Float16* qh   = kh + MAT;                             // 256 KB
    float* pm  = ws + 6 * MAT + 32768 + 2 * 65536;         // 4 MB
    float* ps  = pm + 8 * MAT;                             // 4 MB
    float* out = (float*)d_out;

    prep_wl<<<256, 256, 0, stream>>>(Wl, WlhT);
    linres3<<<dim3(128, 3), 256, 0, stream>>>(key, Wk, bk, kbuf,
                                              query, Wq, bq, qbuf,
                                              value, Wva, bva, vbuf);
    cvt_fp16<<<128, 256, 0, stream>>>(kbuf, qbuf, kh, qh);
    hipMemsetAsync(vs, 0, MAT * sizeof(float), stream);

    stats_mfma<<<dim3(8, 2, 64), 256, 0, stream>>>(qh, kh, WlhT, bl, pm, ps);
    reduce_ms<<<512, 256, 0, stream>>>(pm, ps, mbuf, sbuf);
    accum_mfma<<<dim3(8, 2, 64), 256, 0, stream>>>(qh, kh, WlhT, bl,
                                                   mbuf, sbuf, vbuf, vs);

    linres1<<<128, 256, 0, stream>>>(vs, Wvo, bvo, out);
}